// Round 13
// baseline (378.530 us; speedup 1.0000x reference)
//
#include <hip/hip_runtime.h>

typedef float  f32x4 __attribute__((ext_vector_type(4)));
typedef short  s16x8 __attribute__((ext_vector_type(8)));
typedef unsigned short u16;
typedef u16    u16x4 __attribute__((ext_vector_type(4)));

#define DEVINL __device__ __forceinline__

DEVINL f32x4 ld4nt(const float* p) {
  return __builtin_nontemporal_load(reinterpret_cast<const f32x4*>(p));
}

// RNE bf16 hi/lo split (R5-proven bit recipe)
DEVINL void split1(float f, u16& h, u16& l) {
  unsigned u = __float_as_uint(f);
  unsigned hb = (u + 0x7fffu + ((u >> 16) & 1u)) >> 16;
  float hf = __uint_as_float(hb << 16);
  float d = f - hf;
  unsigned v = __float_as_uint(d);
  unsigned lb = (v + 0x7fffu + ((v >> 16) & 1u)) >> 16;
  h = (u16)hb;
  l = (u16)lb;
}

DEVINL f32x4 bf4_to_f32(u16x4 v) {
  f32x4 r;
  #pragma unroll
  for (int i = 0; i < 4; ++i) r[i] = __uint_as_float(((unsigned)v[i]) << 16);
  return r;
}

// ---------------------------------------------------------------------------
// Fused prep: blocks [0,257) weight prep; [257,257+npack) nfeats->hi/lo planes;
// rest = degree histogram. (R12-proven)
// ---------------------------------------------------------------------------
__global__ __launch_bounds__(256) void prep_kernel(
    const float* __restrict__ Wm1, const float* __restrict__ Wa1, const float* __restrict__ bm1,
    const float* __restrict__ Wm2, const float* __restrict__ Wa2, const float* __restrict__ bm2,
    float* __restrict__ bmw1, float* __restrict__ bmw2,
    u16* __restrict__ w1h, u16* __restrict__ w1l,
    u16* __restrict__ w2h, u16* __restrict__ w2l,
    const float* __restrict__ nf, u16* __restrict__ nfh, u16* __restrict__ nfl,
    int nelem, const int* __restrict__ dst, int* __restrict__ deg, int E, int npack)
{
  int blk = blockIdx.x;
  if (blk < 257) {
    int b = blk * 2 + (threadIdx.x >> 7);   // 0..513
    int j = threadIdx.x & 127;
    u16 h, l;
    if (b < 128) {
      float acc = 0.f;
      for (int k = 0; k < 128; ++k) acc = fmaf(Wm1[b * 128 + k], Wa1[(64 + k) * 128 + j], acc);
      split1(acc, h, l);
      w1h[(size_t)j * 192 + 64 + b] = h;
      w1l[(size_t)j * 192 + 64 + b] = l;
    } else if (b < 320) {
      int i = b - 128;
      float acc = 0.f;
      for (int k = 0; k < 128; ++k) acc = fmaf(Wm2[i * 128 + k], Wa2[(128 + k) * 128 + j], acc);
      split1(acc, h, l);
      w2h[(size_t)j * 320 + 128 + i] = h;
      w2l[(size_t)j * 320 + 128 + i] = l;
    } else if (b == 320) {
      float acc = 0.f;
      for (int k = 0; k < 128; ++k) acc = fmaf(bm1[k], Wa1[(64 + k) * 128 + j], acc);
      bmw1[j] = acc;
    } else if (b == 321) {
      float acc = 0.f;
      for (int k = 0; k < 128; ++k) acc = fmaf(bm2[k], Wa2[(128 + k) * 128 + j], acc);
      bmw2[j] = acc;
    } else if (b < 386) {
      int t = b - 322;
      split1(Wa1[t * 128 + j], h, l);
      w1h[(size_t)j * 192 + t] = h;
      w1l[(size_t)j * 192 + t] = l;
    } else {
      int t = b - 386;
      split1(Wa2[t * 128 + j], h, l);
      w2h[(size_t)j * 320 + t] = h;
      w2l[(size_t)j * 320 + t] = l;
    }
  } else if (blk < 257 + npack) {
    int idx = (blk - 257) * 256 + threadIdx.x;
    if (idx < nelem) {
      u16 h, l;
      split1(nf[idx], h, l);
      nfh[idx] = h;
      nfl[idx] = l;
    }
  } else {
    int e = (blk - 257 - npack) * 256 + threadIdx.x;
    if (e < E) atomicAdd(&deg[dst[e]], 1);
  }
}

// ---------------------------------------------------------------------------
// CSR build (R10-proven)
// ---------------------------------------------------------------------------
__global__ __launch_bounds__(256) void scan_blk_kernel(
    const int* __restrict__ in, int* __restrict__ excl, int* __restrict__ bsum, int n)
{
  __shared__ int tmp[256];
  int t = threadIdx.x;
  int i = blockIdx.x * 256 + t;
  int v = (i < n) ? in[i] : 0;
  tmp[t] = v;
  __syncthreads();
  #pragma unroll
  for (int off = 1; off < 256; off <<= 1) {
    int add = (t >= off) ? tmp[t - off] : 0;
    __syncthreads();
    tmp[t] += add;
    __syncthreads();
  }
  if (i < n) excl[i] = tmp[t] - v;
  if (t == 255) bsum[blockIdx.x] = tmp[255];
}

__global__ __launch_bounds__(256) void finalize2_kernel(
    const int* __restrict__ excl, const int* __restrict__ bsum, int nblk,
    int* __restrict__ rp, int* __restrict__ cursor, int N, int E)
{
  __shared__ int bs[256];
  int t = threadIdx.x;
  bs[t] = (t < nblk) ? bsum[t] : 0;
  __syncthreads();
  #pragma unroll
  for (int off = 1; off < 256; off <<= 1) {
    int add = (t >= off) ? bs[t - off] : 0;
    __syncthreads();
    bs[t] += add;
    __syncthreads();
  }
  int i = blockIdx.x * 256 + t;
  if (i < N) {
    int blk = i >> 8;
    int boff = blk ? bs[blk - 1] : 0;
    int v = excl[i] + boff;
    rp[i] = v;
    cursor[i] = v;
  }
  if (i == N) rp[N] = E;
}

__global__ __launch_bounds__(256) void scatter_kernel(
    const int* __restrict__ dst, const int* __restrict__ src,
    int* __restrict__ cursor, int2* __restrict__ es, int E)
{
  int e = blockIdx.x * 256 + threadIdx.x;
  if (e >= E) return;
  int d = dst[e];
  int pos = atomicAdd(&cursor[d], 1);
  es[pos] = make_int2(e, src[e]);
}

// ---------------------------------------------------------------------------
// Layer-1 mean aggregation (R12-proven): ef fp32 + nf hi-plane.
// ---------------------------------------------------------------------------
__global__ __launch_bounds__(256) void csr_agg_l1_kernel(
    const float* __restrict__ ef, const u16* __restrict__ nfh,
    const int2* __restrict__ es, const int* __restrict__ rp,
    u16* __restrict__ mEh, u16* __restrict__ mEl,
    u16* __restrict__ mH1h, u16* __restrict__ mH1l, int N)
{
  int node = (int)((blockIdx.x * 256u + threadIdx.x) >> 6);
  node = __builtin_amdgcn_readfirstlane(node);
  if (node >= N) return;
  const int lane = threadIdx.x & 63;
  const int g = lane >> 4, l16 = lane & 15;
  const int beg = rp[node], end = rp[node + 1];
  const int full_end = beg + ((end - beg) & ~15);

  f32x4 ea = {0.f, 0.f, 0.f, 0.f}, ha = {0.f, 0.f, 0.f, 0.f};
  int k0 = beg;
  for (; k0 < full_end; k0 += 16) {
    #pragma unroll
    for (int u = 0; u < 4; ++u) {
      int2 p = es[k0 + 4 * u + g];
      ea += ld4nt(ef + (size_t)p.x * 64 + l16 * 4);
      ha += bf4_to_f32(*reinterpret_cast<const u16x4*>(nfh + (size_t)p.y * 64 + l16 * 4));
    }
  }
  #pragma unroll
  for (int u = 0; u < 4; ++u) {
    int i = k0 + 4 * u + g;
    if (i < end) {
      int2 p = es[i];
      ea += ld4nt(ef + (size_t)p.x * 64 + l16 * 4);
      ha += bf4_to_f32(*reinterpret_cast<const u16x4*>(nfh + (size_t)p.y * 64 + l16 * 4));
    }
  }
  #pragma unroll
  for (int j = 0; j < 4; ++j) {
    ea[j] += __shfl_xor(ea[j], 16);
    ea[j] += __shfl_xor(ea[j], 32);
    ha[j] += __shfl_xor(ha[j], 16);
    ha[j] += __shfl_xor(ha[j], 32);
  }
  if (g == 0) {
    float inv = 1.0f / fmaxf((float)(end - beg), 1.0f);
    u16x4 eh, el, hh, hl;
    #pragma unroll
    for (int j = 0; j < 4; ++j) {
      u16 a, b;
      split1(ea[j] * inv, a, b); eh[j] = a; el[j] = b;
      split1(ha[j] * inv, a, b); hh[j] = a; hl[j] = b;
    }
    size_t o = (size_t)node * 64 + l16 * 4;
    *reinterpret_cast<u16x4*>(mEh  + o) = eh;
    *reinterpret_cast<u16x4*>(mEl  + o) = el;
    *reinterpret_cast<u16x4*>(mH1h + o) = hh;
    *reinterpret_cast<u16x4*>(mH1l + o) = hl;
  }
}

// ---------------------------------------------------------------------------
// Layer-2 mean aggregation (R12-proven): h1 hi-plane only, 16 deep.
// ---------------------------------------------------------------------------
__global__ __launch_bounds__(256) void csr_agg128_kernel(
    const u16* __restrict__ h1h, const int2* __restrict__ es,
    const int* __restrict__ rp, u16* __restrict__ mH2h, u16* __restrict__ mH2l, int N)
{
  int node = (int)((blockIdx.x * 256u + threadIdx.x) >> 6);
  node = __builtin_amdgcn_readfirstlane(node);
  if (node >= N) return;
  const int lane = threadIdx.x & 63;
  const int g = lane >> 5, l32 = lane & 31;
  const int beg = rp[node], end = rp[node + 1];
  const int full_end = beg + ((end - beg) & ~15);

  f32x4 a = {0.f, 0.f, 0.f, 0.f};
  int k0 = beg;
  for (; k0 < full_end; k0 += 16) {
    u16x4 v[8];
    #pragma unroll
    for (int u = 0; u < 8; ++u) {
      int s = es[k0 + 2 * u + g].y;
      v[u] = *reinterpret_cast<const u16x4*>(h1h + (size_t)s * 128 + l32 * 4);
    }
    #pragma unroll
    for (int u = 0; u < 8; ++u) a += bf4_to_f32(v[u]);
  }
  #pragma unroll
  for (int u = 0; u < 8; ++u) {
    int i = k0 + 2 * u + g;
    if (i < end) {
      int s = es[i].y;
      a += bf4_to_f32(*reinterpret_cast<const u16x4*>(h1h + (size_t)s * 128 + l32 * 4));
    }
  }
  #pragma unroll
  for (int j = 0; j < 4; ++j) a[j] += __shfl_xor(a[j], 32);
  if (g == 0) {
    float inv = 1.0f / fmaxf((float)(end - beg), 1.0f);
    u16x4 ph, pl;
    #pragma unroll
    for (int j = 0; j < 4; ++j) {
      u16 x, y;
      split1(a[j] * inv, x, y);
      ph[j] = x; pl[j] = y;
    }
    size_t o = (size_t)node * 128 + l32 * 4;
    *reinterpret_cast<u16x4*>(mH2h + o) = ph;
    *reinterpret_cast<u16x4*>(mH2l + o) = pl;
  }
}

// ---------------------------------------------------------------------------
// Layer-1 fused GEMM: 64-row blocks, 4 waves x (16 rows x 128 cols).
// Grid doubled vs R12 -> ~3 waves/SIMD for latency hiding.
// ---------------------------------------------------------------------------
template<int C1, int C2, int C3>
__global__ __launch_bounds__(256, 2) void fgemm_kernel(
    const u16* __restrict__ X1h, const u16* __restrict__ X1l,
    const u16* __restrict__ X2h, const u16* __restrict__ X2l,
    const u16* __restrict__ X3h, const u16* __restrict__ X3l,
    const u16* __restrict__ WtHi, const u16* __restrict__ WtLo,
    const float* __restrict__ ba, const float* __restrict__ bmw,
    const int* __restrict__ deg, u16* __restrict__ outH, u16* __restrict__ outL, int n)
{
  constexpr int K = C1 + C2 + C3;
  const int lane = threadIdx.x & 63;
  const int w = threadIdx.x >> 6;
  const int base = blockIdx.x * 64;
  const int l15 = lane & 15;
  const int lg = lane >> 4;

  f32x4 acc[8] = {};

  #pragma unroll
  for (int k0 = 0; k0 < K; k0 += 32) {
    const u16 *sph, *spl;
    int C, off;
    if (k0 < C1)            { sph = X1h; spl = X1l; C = C1; off = k0; }
    else if (k0 < C1 + C2)  { sph = X2h; spl = X2l; C = C2; off = k0 - C1; }
    else                    { sph = X3h; spl = X3l; C = C3; off = k0 - C1 - C2; }
    const int ca = off + lg * 8;

    int row = base + w * 16 + l15;
    if (row >= n) row = n - 1;
    s16x8 ah = *reinterpret_cast<const s16x8*>(sph + (size_t)row * C + ca);
    s16x8 al = *reinterpret_cast<const s16x8*>(spl + (size_t)row * C + ca);

    s16x8 bh[8], bl[8];
    const int kb = k0 + lg * 8;
    #pragma unroll
    for (int ni = 0; ni < 8; ++ni) {
      size_t woff = (size_t)(ni * 16 + l15) * K + kb;
      bh[ni] = *reinterpret_cast<const s16x8*>(WtHi + woff);
      bl[ni] = *reinterpret_cast<const s16x8*>(WtLo + woff);
    }

    #pragma unroll
    for (int ni = 0; ni < 8; ++ni) {
      acc[ni] = __builtin_amdgcn_mfma_f32_16x16x32_bf16(ah, bh[ni], acc[ni], 0, 0, 0);
      acc[ni] = __builtin_amdgcn_mfma_f32_16x16x32_bf16(ah, bl[ni], acc[ni], 0, 0, 0);
      acc[ni] = __builtin_amdgcn_mfma_f32_16x16x32_bf16(al, bh[ni], acc[ni], 0, 0, 0);
    }
  }

  float bav[8], bmv[8];
  #pragma unroll
  for (int ni = 0; ni < 8; ++ni) {
    bav[ni] = ba[ni * 16 + l15];
    bmv[ni] = bmw[ni * 16 + l15];
  }

  #pragma unroll
  for (int r = 0; r < 4; ++r) {
    int grow = base + w * 16 + lg * 4 + r;
    if (grow >= n) continue;
    float msk = deg[grow] > 0 ? 1.0f : 0.0f;
    u16* oph = outH + (size_t)grow * 128 + l15;
    u16* opl = outL + (size_t)grow * 128 + l15;
    #pragma unroll
    for (int ni = 0; ni < 8; ++ni) {
      float v = fmaxf(acc[ni][r] + bav[ni] + msk * bmv[ni], 0.0f);
      u16 h, l;
      split1(v, h, l);
      oph[ni * 16] = h;
      opl[ni * 16] = l;
    }
  }
}

// ---------------------------------------------------------------------------
// Layer-2 fused GEMM + predictor projection: 64-row blocks.
// h2 tile (64x129 LDS) -> pt[n][20]; bp folded into dst half.
// ---------------------------------------------------------------------------
__global__ __launch_bounds__(256, 2) void fgemm2_pred_kernel(
    const u16* __restrict__ X1h, const u16* __restrict__ X1l,
    const u16* __restrict__ X2h, const u16* __restrict__ X2l,
    const u16* __restrict__ X3h, const u16* __restrict__ X3l,
    const u16* __restrict__ WtHi, const u16* __restrict__ WtLo,
    const float* __restrict__ ba, const float* __restrict__ bmw,
    const int* __restrict__ deg, const float* __restrict__ Wp,
    const float* __restrict__ bp, float* __restrict__ pt, int n)
{
  constexpr int C1 = 128, C2 = 128, C3 = 64;
  constexpr int K = C1 + C2 + C3;
  __shared__ float xs[64 * 129];
  __shared__ float wl[2560];

  const int tid = threadIdx.x;
  const int lane = tid & 63;
  const int w = tid >> 6;
  const int base = blockIdx.x * 64;
  const int l15 = lane & 15;
  const int lg = lane >> 4;

  for (int i = tid; i < 2560; i += 256) wl[i] = Wp[i];

  f32x4 acc[8] = {};

  #pragma unroll
  for (int k0 = 0; k0 < K; k0 += 32) {
    const u16 *sph, *spl;
    int C, off;
    if (k0 < C1)            { sph = X1h; spl = X1l; C = C1; off = k0; }
    else if (k0 < C1 + C2)  { sph = X2h; spl = X2l; C = C2; off = k0 - C1; }
    else                    { sph = X3h; spl = X3l; C = C3; off = k0 - C1 - C2; }
    const int ca = off + lg * 8;

    int row = base + w * 16 + l15;
    if (row >= n) row = n - 1;
    s16x8 ah = *reinterpret_cast<const s16x8*>(sph + (size_t)row * C + ca);
    s16x8 al = *reinterpret_cast<const s16x8*>(spl + (size_t)row * C + ca);

    s16x8 bh[8], bl[8];
    const int kb = k0 + lg * 8;
    #pragma unroll
    for (int ni = 0; ni < 8; ++ni) {
      size_t woff = (size_t)(ni * 16 + l15) * K + kb;
      bh[ni] = *reinterpret_cast<const s16x8*>(WtHi + woff);
      bl[ni] = *reinterpret_cast<const s16x8*>(WtLo + woff);
    }

    #pragma unroll
    for (int ni = 0; ni < 8; ++ni) {
      acc[ni] = __builtin_amdgcn_mfma_f32_16x16x32_bf16(ah, bh[ni], acc[ni], 0, 0, 0);
      acc[ni] = __builtin_amdgcn_mfma_f32_16x16x32_bf16(ah, bl[ni], acc[ni], 0, 0, 0);
      acc[ni] = __builtin_amdgcn_mfma_f32_16x16x32_bf16(al, bh[ni], acc[ni], 0, 0, 0);
    }
  }

  float bav[8], bmv[8];
  #pragma unroll
  for (int ni = 0; ni < 8; ++ni) {
    bav[ni] = ba[ni * 16 + l15];
    bmv[ni] = bmw[ni * 16 + l15];
  }

  #pragma unroll
  for (int r = 0; r < 4; ++r) {
    int lr = w * 16 + lg * 4 + r;
    int grow = base + lr;
    if (grow >= n) continue;
    float msk = deg[grow] > 0 ? 1.0f : 0.0f;
    #pragma unroll
    for (int ni = 0; ni < 8; ++ni)
      xs[lr * 129 + ni * 16 + l15] =
          fmaxf(acc[ni][r] + bav[ni] + msk * bmv[ni], 0.0f);
  }
  __syncthreads();

  // predictor: 256 threads = 64 rows x 4 chunks of 5 cols
  const int r = tid >> 2;
  const int c = tid & 3;
  const int half = c >> 1;
  const int jb = (c & 1) * 5;
  const int grow = base + r;
  if (grow < n) {
    const float* wb = wl + half * 1280 + jb;
    float a[5] = {};
    for (int k = 0; k < 128; ++k) {
      float x = xs[r * 129 + k];
      #pragma unroll
      for (int j = 0; j < 5; ++j) a[j] = fmaf(x, wb[k * 10 + j], a[j]);
    }
    float* op = pt + (size_t)grow * 20 + half * 10 + jb;
    if (half) {
      #pragma unroll
      for (int j = 0; j < 5; ++j) op[j] = a[j] + bp[jb + j];
    } else {
      #pragma unroll
      for (int j = 0; j < 5; ++j) op[j] = a[j];
    }
  }
}

// ---------------------------------------------------------------------------
// Edge predictor (bp pre-folded)
// ---------------------------------------------------------------------------
__global__ __launch_bounds__(256) void pred_edge_kernel(
    const float* __restrict__ pt, const int* __restrict__ src, const int* __restrict__ dst,
    float* __restrict__ out, int E)
{
  int idx = blockIdx.x * 256 + threadIdx.x;
  if (idx >= E * 5) return;
  int e = idx / 5;
  int jj = idx - e * 5;
  int s = src[e], d = dst[e];
  const float2* p2 = (const float2*)pt;
  float2 a = p2[(size_t)s * 10 + jj];
  float2 b = p2[(size_t)d * 10 + 5 + jj];
  ((float2*)out)[idx] = make_float2(a.x + b.x, a.y + b.y);
}

extern "C" void kernel_launch(void* const* d_in, const int* in_sizes, int n_in,
                              void* d_out, int out_size, void* d_ws, size_t ws_size,
                              hipStream_t stream) {
  const float* nfeats = (const float*)d_in[0];
  const float* efeats = (const float*)d_in[1];
  const int*   src    = (const int*)d_in[2];
  const int*   dst    = (const int*)d_in[3];
  const float* Wm1 = (const float*)d_in[4];
  const float* bm1 = (const float*)d_in[5];
  const float* Wa1 = (const float*)d_in[6];
  const float* ba1 = (const float*)d_in[7];
  const float* Wm2 = (const float*)d_in[8];
  const float* bm2 = (const float*)d_in[9];
  const float* Wa2 = (const float*)d_in[10];
  const float* ba2 = (const float*)d_in[11];
  const float* Wp  = (const float*)d_in[12];
  const float* bp  = (const float*)d_in[13];

  const int N = in_sizes[0] / 64;
  const int E = in_sizes[2];
  const int nblk = (N + 255) / 256;

  // ---- int region (R5..R12-proven layout) ----
  int* ip     = (int*)d_ws;
  int* deg_i  = ip;                                  // N
  int* rp     = ip + (size_t)N;                      // N+1 (padded to +4)
  int* scr    = ip + 2 * (size_t)N + 4 + E;          // 2N+512 CSR scratch
  int* excl   = scr;                                 // N
  int* cursor = scr + (size_t)N;                     // N
  int* bsum   = scr + 2 * (size_t)N;                 // 256

  // ---- plane region (R12-proven layout) ----
  size_t fbase = (4 * (size_t)N + 516 + (size_t)E + 3) & ~(size_t)3;
  float* fp   = (float*)d_ws;
  u16* mEh  = (u16*)(fp + fbase);                       // N*64 u16
  u16* mEl  = mEh + (size_t)N * 64;                     // N*64 u16
  float* pt = fp + fbase + (size_t)N * 64;              // N*20 f32 (overlays mH1 slot)
  u16* mH1h = (u16*)pt;                                 // N*64 u16
  u16* mH1l = mH1h + (size_t)N * 64;                    // N*64 u16
  u16* mH2h = (u16*)(fp + fbase + (size_t)N * 128);     // N*128 u16
  u16* mH2l = mH2h + (size_t)N * 128;                   // N*128 u16
  u16* h1h  = (u16*)(fp + fbase + (size_t)N * 384);     // N*128 u16
  u16* h1l  = h1h + (size_t)N * 128;                    // N*128 u16
  float* out = (float*)d_out;

  // es (int2), weights, nf planes appended after float slots
  int2*  es   = (int2*)(fp + fbase + (size_t)N * 512);
  float* wst  = fp + fbase + (size_t)N * 512 + 2 * (size_t)E;
  float* bmw1 = wst;                    // 128
  float* bmw2 = bmw1 + 128;             // 128
  u16* w1h = (u16*)(bmw2 + 128);        // [128][192]
  u16* w1l = w1h + 192 * 128;
  u16* w2h = w1l + 192 * 128;           // [128][320]
  u16* w2l = w2h + 320 * 128;
  u16* nfh = w2l + 320 * 128;           // N*64 u16
  u16* nfl = nfh + (size_t)N * 64;      // N*64 u16

  hipMemsetAsync(deg_i, 0, (size_t)N * sizeof(int), stream);

  int gridE  = (E + 255) / 256;
  int gridN  = (N + 63) / 64;            // 64-row GEMM blocks
  int gridNW = ((N * 64) + 255) / 256;
  int npack  = (N * 64 + 255) / 256;

  // fused prep: weight prep + nfeats plane split + degree histogram
  prep_kernel<<<257 + npack + gridE, 256, 0, stream>>>(
      Wm1, Wa1, bm1, Wm2, Wa2, bm2, bmw1, bmw2, w1h, w1l, w2h, w2l,
      nfeats, nfh, nfl, N * 64, dst, deg_i, E, npack);

  // CSR build
  scan_blk_kernel<<<nblk, 256, 0, stream>>>(deg_i, excl, bsum, N);
  finalize2_kernel<<<(N + 256) / 256, 256, 0, stream>>>(excl, bsum, nblk, rp, cursor, N, E);
  scatter_kernel<<<gridE, 256, 0, stream>>>(dst, src, cursor, es, E);

  // layer 1
  csr_agg_l1_kernel<<<gridNW, 256, 0, stream>>>(
      efeats, nfh, es, rp, mEh, mEl, mH1h, mH1l, N);
  fgemm_kernel<64, 64, 64><<<gridN, 256, 0, stream>>>(
      nfh, nfl, mH1h, mH1l, mEh, mEl, w1h, w1l, ba1, bmw1, deg_i, h1h, h1l, N);

  // layer 2 (+ fused predictor projection; h2 never materialized)
  csr_agg128_kernel<<<gridNW, 256, 0, stream>>>(h1h, es, rp, mH2h, mH2l, N);
  fgemm2_pred_kernel<<<gridN, 256, 0, stream>>>(
      h1h, h1l, mH2h, mH2l, mEh, mEl, w2h, w2l, ba2, bmw2, deg_i, Wp, bp, pt, N);

  // edge scores
  pred_edge_kernel<<<(E * 5 + 255) / 256, 256, 0, stream>>>(pt, src, dst, out, E);
}

// Round 14
// 284.676 us; speedup vs baseline: 1.3297x; 1.3297x over previous
//
#include <hip/hip_runtime.h>

typedef float  f32x4 __attribute__((ext_vector_type(4)));
typedef short  s16x8 __attribute__((ext_vector_type(8)));
typedef unsigned short u16;
typedef u16    u16x4 __attribute__((ext_vector_type(4)));
typedef u16    u16x8 __attribute__((ext_vector_type(8)));

#define DEVINL __device__ __forceinline__

DEVINL f32x4 ld4nt(const float* p) {
  return __builtin_nontemporal_load(reinterpret_cast<const f32x4*>(p));
}

// RNE bf16 hi/lo split (R5-proven bit recipe)
DEVINL void split1(float f, u16& h, u16& l) {
  unsigned u = __float_as_uint(f);
  unsigned hb = (u + 0x7fffu + ((u >> 16) & 1u)) >> 16;
  float hf = __uint_as_float(hb << 16);
  float d = f - hf;
  unsigned v = __float_as_uint(d);
  unsigned lb = (v + 0x7fffu + ((v >> 16) & 1u)) >> 16;
  h = (u16)hb;
  l = (u16)lb;
}

DEVINL f32x4 bf4_to_f32(u16x4 v) {
  f32x4 r;
  #pragma unroll
  for (int i = 0; i < 4; ++i) r[i] = __uint_as_float(((unsigned)v[i]) << 16);
  return r;
}

// ---------------------------------------------------------------------------
// Fused prep (R12-proven): weight prep + nfeats plane split + degree histogram
// ---------------------------------------------------------------------------
__global__ __launch_bounds__(256) void prep_kernel(
    const float* __restrict__ Wm1, const float* __restrict__ Wa1, const float* __restrict__ bm1,
    const float* __restrict__ Wm2, const float* __restrict__ Wa2, const float* __restrict__ bm2,
    float* __restrict__ bmw1, float* __restrict__ bmw2,
    u16* __restrict__ w1h, u16* __restrict__ w1l,
    u16* __restrict__ w2h, u16* __restrict__ w2l,
    const float* __restrict__ nf, u16* __restrict__ nfh, u16* __restrict__ nfl,
    int nelem, const int* __restrict__ dst, int* __restrict__ deg, int E, int npack)
{
  int blk = blockIdx.x;
  if (blk < 257) {
    int b = blk * 2 + (threadIdx.x >> 7);   // 0..513
    int j = threadIdx.x & 127;
    u16 h, l;
    if (b < 128) {
      float acc = 0.f;
      for (int k = 0; k < 128; ++k) acc = fmaf(Wm1[b * 128 + k], Wa1[(64 + k) * 128 + j], acc);
      split1(acc, h, l);
      w1h[(size_t)j * 192 + 64 + b] = h;
      w1l[(size_t)j * 192 + 64 + b] = l;
    } else if (b < 320) {
      int i = b - 128;
      float acc = 0.f;
      for (int k = 0; k < 128; ++k) acc = fmaf(Wm2[i * 128 + k], Wa2[(128 + k) * 128 + j], acc);
      split1(acc, h, l);
      w2h[(size_t)j * 320 + 128 + i] = h;
      w2l[(size_t)j * 320 + 128 + i] = l;
    } else if (b == 320) {
      float acc = 0.f;
      for (int k = 0; k < 128; ++k) acc = fmaf(bm1[k], Wa1[(64 + k) * 128 + j], acc);
      bmw1[j] = acc;
    } else if (b == 321) {
      float acc = 0.f;
      for (int k = 0; k < 128; ++k) acc = fmaf(bm2[k], Wa2[(128 + k) * 128 + j], acc);
      bmw2[j] = acc;
    } else if (b < 386) {
      int t = b - 322;
      split1(Wa1[t * 128 + j], h, l);
      w1h[(size_t)j * 192 + t] = h;
      w1l[(size_t)j * 192 + t] = l;
    } else {
      int t = b - 386;
      split1(Wa2[t * 128 + j], h, l);
      w2h[(size_t)j * 320 + t] = h;
      w2l[(size_t)j * 320 + t] = l;
    }
  } else if (blk < 257 + npack) {
    int idx = (blk - 257) * 256 + threadIdx.x;
    if (idx < nelem) {
      u16 h, l;
      split1(nf[idx], h, l);
      nfh[idx] = h;
      nfl[idx] = l;
    }
  } else {
    int e = (blk - 257 - npack) * 256 + threadIdx.x;
    if (e < E) atomicAdd(&deg[dst[e]], 1);
  }
}

// ---------------------------------------------------------------------------
// CSR build (R10-proven)
// ---------------------------------------------------------------------------
__global__ __launch_bounds__(256) void scan_blk_kernel(
    const int* __restrict__ in, int* __restrict__ excl, int* __restrict__ bsum, int n)
{
  __shared__ int tmp[256];
  int t = threadIdx.x;
  int i = blockIdx.x * 256 + t;
  int v = (i < n) ? in[i] : 0;
  tmp[t] = v;
  __syncthreads();
  #pragma unroll
  for (int off = 1; off < 256; off <<= 1) {
    int add = (t >= off) ? tmp[t - off] : 0;
    __syncthreads();
    tmp[t] += add;
    __syncthreads();
  }
  if (i < n) excl[i] = tmp[t] - v;
  if (t == 255) bsum[blockIdx.x] = tmp[255];
}

__global__ __launch_bounds__(256) void finalize2_kernel(
    const int* __restrict__ excl, const int* __restrict__ bsum, int nblk,
    int* __restrict__ rp, int* __restrict__ cursor, int N, int E)
{
  __shared__ int bs[256];
  int t = threadIdx.x;
  bs[t] = (t < nblk) ? bsum[t] : 0;
  __syncthreads();
  #pragma unroll
  for (int off = 1; off < 256; off <<= 1) {
    int add = (t >= off) ? bs[t - off] : 0;
    __syncthreads();
    bs[t] += add;
    __syncthreads();
  }
  int i = blockIdx.x * 256 + t;
  if (i < N) {
    int blk = i >> 8;
    int boff = blk ? bs[blk - 1] : 0;
    int v = excl[i] + boff;
    rp[i] = v;
    cursor[i] = v;
  }
  if (i == N) rp[N] = E;
}

__global__ __launch_bounds__(256) void scatter_kernel(
    const int* __restrict__ dst, const int* __restrict__ src,
    int* __restrict__ cursor, int2* __restrict__ es, int E)
{
  int e = blockIdx.x * 256 + threadIdx.x;
  if (e >= E) return;
  int d = dst[e];
  int pos = atomicAdd(&cursor[d], 1);
  es[pos] = make_int2(e, src[e]);
}

// ---------------------------------------------------------------------------
// Layer-1 mean aggregation (R12-proven): ef fp32 + nf hi-plane.
// ---------------------------------------------------------------------------
__global__ __launch_bounds__(256) void csr_agg_l1_kernel(
    const float* __restrict__ ef, const u16* __restrict__ nfh,
    const int2* __restrict__ es, const int* __restrict__ rp,
    u16* __restrict__ mEh, u16* __restrict__ mEl,
    u16* __restrict__ mH1h, u16* __restrict__ mH1l, int N)
{
  int node = (int)((blockIdx.x * 256u + threadIdx.x) >> 6);
  node = __builtin_amdgcn_readfirstlane(node);
  if (node >= N) return;
  const int lane = threadIdx.x & 63;
  const int g = lane >> 4, l16 = lane & 15;
  const int beg = rp[node], end = rp[node + 1];
  const int full_end = beg + ((end - beg) & ~15);

  f32x4 ea = {0.f, 0.f, 0.f, 0.f}, ha = {0.f, 0.f, 0.f, 0.f};
  int k0 = beg;
  for (; k0 < full_end; k0 += 16) {
    #pragma unroll
    for (int u = 0; u < 4; ++u) {
      int2 p = es[k0 + 4 * u + g];
      ea += ld4nt(ef + (size_t)p.x * 64 + l16 * 4);
      ha += bf4_to_f32(*reinterpret_cast<const u16x4*>(nfh + (size_t)p.y * 64 + l16 * 4));
    }
  }
  #pragma unroll
  for (int u = 0; u < 4; ++u) {
    int i = k0 + 4 * u + g;
    if (i < end) {
      int2 p = es[i];
      ea += ld4nt(ef + (size_t)p.x * 64 + l16 * 4);
      ha += bf4_to_f32(*reinterpret_cast<const u16x4*>(nfh + (size_t)p.y * 64 + l16 * 4));
    }
  }
  #pragma unroll
  for (int j = 0; j < 4; ++j) {
    ea[j] += __shfl_xor(ea[j], 16);
    ea[j] += __shfl_xor(ea[j], 32);
    ha[j] += __shfl_xor(ha[j], 16);
    ha[j] += __shfl_xor(ha[j], 32);
  }
  if (g == 0) {
    float inv = 1.0f / fmaxf((float)(end - beg), 1.0f);
    u16x4 eh, el, hh, hl;
    #pragma unroll
    for (int j = 0; j < 4; ++j) {
      u16 a, b;
      split1(ea[j] * inv, a, b); eh[j] = a; el[j] = b;
      split1(ha[j] * inv, a, b); hh[j] = a; hl[j] = b;
    }
    size_t o = (size_t)node * 64 + l16 * 4;
    *reinterpret_cast<u16x4*>(mEh  + o) = eh;
    *reinterpret_cast<u16x4*>(mEl  + o) = el;
    *reinterpret_cast<u16x4*>(mH1h + o) = hh;
    *reinterpret_cast<u16x4*>(mH1l + o) = hl;
  }
}

// ---------------------------------------------------------------------------
// Layer-2 mean aggregation (R12-proven): h1 hi-plane only, 16 deep.
// ---------------------------------------------------------------------------
__global__ __launch_bounds__(256) void csr_agg128_kernel(
    const u16* __restrict__ h1h, const int2* __restrict__ es,
    const int* __restrict__ rp, u16* __restrict__ mH2h, u16* __restrict__ mH2l, int N)
{
  int node = (int)((blockIdx.x * 256u + threadIdx.x) >> 6);
  node = __builtin_amdgcn_readfirstlane(node);
  if (node >= N) return;
  const int lane = threadIdx.x & 63;
  const int g = lane >> 5, l32 = lane & 31;
  const int beg = rp[node], end = rp[node + 1];
  const int full_end = beg + ((end - beg) & ~15);

  f32x4 a = {0.f, 0.f, 0.f, 0.f};
  int k0 = beg;
  for (; k0 < full_end; k0 += 16) {
    u16x4 v[8];
    #pragma unroll
    for (int u = 0; u < 8; ++u) {
      int s = es[k0 + 2 * u + g].y;
      v[u] = *reinterpret_cast<const u16x4*>(h1h + (size_t)s * 128 + l32 * 4);
    }
    #pragma unroll
    for (int u = 0; u < 8; ++u) a += bf4_to_f32(v[u]);
  }
  #pragma unroll
  for (int u = 0; u < 8; ++u) {
    int i = k0 + 2 * u + g;
    if (i < end) {
      int s = es[i].y;
      a += bf4_to_f32(*reinterpret_cast<const u16x4*>(h1h + (size_t)s * 128 + l32 * 4));
    }
  }
  #pragma unroll
  for (int j = 0; j < 4; ++j) a[j] += __shfl_xor(a[j], 32);
  if (g == 0) {
    float inv = 1.0f / fmaxf((float)(end - beg), 1.0f);
    u16x4 ph, pl;
    #pragma unroll
    for (int j = 0; j < 4; ++j) {
      u16 x, y;
      split1(a[j] * inv, x, y);
      ph[j] = x; pl[j] = y;
    }
    size_t o = (size_t)node * 128 + l32 * 4;
    *reinterpret_cast<u16x4*>(mH2h + o) = ph;
    *reinterpret_cast<u16x4*>(mH2l + o) = pl;
  }
}

// ---------------------------------------------------------------------------
// Cooperative B-tile stage: [128 cols][32 k] both planes into LDS, pad 40 u16.
// 256 threads: col = tid&127, k-half = tid>>7; 4x16B global, 4x16B ds_write.
// ---------------------------------------------------------------------------
DEVINL void stage_b(const u16* __restrict__ WtHi, const u16* __restrict__ WtLo,
                    int K, int k0, int tid, u16* bsh, u16* bsl) {
  int col = tid & 127;
  int kh  = (tid >> 7) & 1;
  const u16* gh = WtHi + (size_t)col * K + k0 + kh * 16;
  const u16* gl = WtLo + (size_t)col * K + k0 + kh * 16;
  int o = col * 40 + kh * 16;
  *reinterpret_cast<u16x8*>(&bsh[o])     = *reinterpret_cast<const u16x8*>(gh);
  *reinterpret_cast<u16x8*>(&bsh[o + 8]) = *reinterpret_cast<const u16x8*>(gh + 8);
  *reinterpret_cast<u16x8*>(&bsl[o])     = *reinterpret_cast<const u16x8*>(gl);
  *reinterpret_cast<u16x8*>(&bsl[o + 8]) = *reinterpret_cast<const u16x8*>(gl + 8);
}

// ---------------------------------------------------------------------------
// Layer-1 fused GEMM (R12 structure: 128-row blocks, 4 waves x 32 rows),
// B-tile LDS-staged: per-wave VMEM ops per k0 drop 20 -> 8.
// ---------------------------------------------------------------------------
template<int C1, int C2, int C3>
__global__ __launch_bounds__(256, 2) void fgemm_kernel(
    const u16* __restrict__ X1h, const u16* __restrict__ X1l,
    const u16* __restrict__ X2h, const u16* __restrict__ X2l,
    const u16* __restrict__ X3h, const u16* __restrict__ X3l,
    const u16* __restrict__ WtHi, const u16* __restrict__ WtLo,
    const float* __restrict__ ba, const float* __restrict__ bmw,
    const int* __restrict__ deg, u16* __restrict__ outH, u16* __restrict__ outL, int n)
{
  constexpr int K = C1 + C2 + C3;
  __shared__ __attribute__((aligned(16))) u16 bsh[128 * 40];
  __shared__ __attribute__((aligned(16))) u16 bsl[128 * 40];

  const int tid = threadIdx.x;
  const int lane = tid & 63;
  const int w = tid >> 6;
  const int base = blockIdx.x * 128;
  const int l15 = lane & 15;
  const int lg = lane >> 4;

  f32x4 acc[2][8] = {};

  #pragma unroll
  for (int k0 = 0; k0 < K; k0 += 32) {
    __syncthreads();                       // previous tile fully consumed
    stage_b(WtHi, WtLo, K, k0, tid, bsh, bsl);
    __syncthreads();

    const u16 *sph, *spl;
    int C, off;
    if (k0 < C1)            { sph = X1h; spl = X1l; C = C1; off = k0; }
    else if (k0 < C1 + C2)  { sph = X2h; spl = X2l; C = C2; off = k0 - C1; }
    else                    { sph = X3h; spl = X3l; C = C3; off = k0 - C1 - C2; }
    const int ca = off + lg * 8;

    s16x8 ah[2], al[2];
    #pragma unroll
    for (int mi = 0; mi < 2; ++mi) {
      int row = base + w * 32 + mi * 16 + l15;
      if (row >= n) row = n - 1;
      ah[mi] = *reinterpret_cast<const s16x8*>(sph + (size_t)row * C + ca);
      al[mi] = *reinterpret_cast<const s16x8*>(spl + (size_t)row * C + ca);
    }

    s16x8 bh[8], bl[8];
    #pragma unroll
    for (int ni = 0; ni < 8; ++ni) {
      int lo = (ni * 16 + l15) * 40 + lg * 8;
      bh[ni] = *reinterpret_cast<const s16x8*>(&bsh[lo]);
      bl[ni] = *reinterpret_cast<const s16x8*>(&bsl[lo]);
    }

    #pragma unroll
    for (int mi = 0; mi < 2; ++mi)
      #pragma unroll
      for (int ni = 0; ni < 8; ++ni) {
        acc[mi][ni] = __builtin_amdgcn_mfma_f32_16x16x32_bf16(ah[mi], bh[ni], acc[mi][ni], 0, 0, 0);
        acc[mi][ni] = __builtin_amdgcn_mfma_f32_16x16x32_bf16(ah[mi], bl[ni], acc[mi][ni], 0, 0, 0);
        acc[mi][ni] = __builtin_amdgcn_mfma_f32_16x16x32_bf16(al[mi], bh[ni], acc[mi][ni], 0, 0, 0);
      }
  }

  float bav[8], bmv[8];
  #pragma unroll
  for (int ni = 0; ni < 8; ++ni) {
    bav[ni] = ba[ni * 16 + l15];
    bmv[ni] = bmw[ni * 16 + l15];
  }

  #pragma unroll
  for (int mi = 0; mi < 2; ++mi) {
    #pragma unroll
    for (int r = 0; r < 4; ++r) {
      int grow = base + w * 32 + mi * 16 + lg * 4 + r;
      if (grow >= n) continue;
      float msk = deg[grow] > 0 ? 1.0f : 0.0f;
      u16* oph = outH + (size_t)grow * 128 + l15;
      u16* opl = outL + (size_t)grow * 128 + l15;
      #pragma unroll
      for (int ni = 0; ni < 8; ++ni) {
        float v = fmaxf(acc[mi][ni][r] + bav[ni] + msk * bmv[ni], 0.0f);
        u16 h, l;
        split1(v, h, l);
        oph[ni * 16] = h;
        opl[ni * 16] = l;
      }
    }
  }
}

// ---------------------------------------------------------------------------
// Layer-2 fused GEMM + predictor projection (R12 structure, 128-row blocks).
// B-tile staged into the xs LDS (dead during K-loop; 20KB <= 66KB).
// ---------------------------------------------------------------------------
__global__ __launch_bounds__(256, 2) void fgemm2_pred_kernel(
    const u16* __restrict__ X1h, const u16* __restrict__ X1l,
    const u16* __restrict__ X2h, const u16* __restrict__ X2l,
    const u16* __restrict__ X3h, const u16* __restrict__ X3l,
    const u16* __restrict__ WtHi, const u16* __restrict__ WtLo,
    const float* __restrict__ ba, const float* __restrict__ bmw,
    const int* __restrict__ deg, const float* __restrict__ Wp,
    const float* __restrict__ bp, float* __restrict__ pt, int n)
{
  constexpr int C1 = 128, C2 = 128, C3 = 64;
  constexpr int K = C1 + C2 + C3;
  __shared__ __attribute__((aligned(16))) float xs[128 * 129];
  __shared__ float wl[2560];
  u16* bsh = reinterpret_cast<u16*>(xs);        // union: B-tile lives in xs
  u16* bsl = bsh + 128 * 40;                    // during the K-loop only

  const int tid = threadIdx.x;
  const int lane = tid & 63;
  const int w = tid >> 6;
  const int base = blockIdx.x * 128;
  const int l15 = lane & 15;
  const int lg = lane >> 4;

  for (int i = tid; i < 2560; i += 256) wl[i] = Wp[i];

  f32x4 acc[2][8] = {};

  #pragma unroll
  for (int k0 = 0; k0 < K; k0 += 32) {
    __syncthreads();
    stage_b(WtHi, WtLo, K, k0, tid, bsh, bsl);
    __syncthreads();

    const u16 *sph, *spl;
    int C, off;
    if (k0 < C1)            { sph = X1h; spl = X1l; C = C1; off = k0; }
    else if (k0 < C1 + C2)  { sph = X2h; spl = X2l; C = C2; off = k0 - C1; }
    else                    { sph = X3h; spl = X3l; C = C3; off = k0 - C1 - C2; }
    const int ca = off + lg * 8;

    s16x8 ah[2], al[2];
    #pragma unroll
    for (int mi = 0; mi < 2; ++mi) {
      int row = base + w * 32 + mi * 16 + l15;
      if (row >= n) row = n - 1;
      ah[mi] = *reinterpret_cast<const s16x8*>(sph + (size_t)row * C + ca);
      al[mi] = *reinterpret_cast<const s16x8*>(spl + (size_t)row * C + ca);
    }

    s16x8 bh[8], bl[8];
    #pragma unroll
    for (int ni = 0; ni < 8; ++ni) {
      int lo = (ni * 16 + l15) * 40 + lg * 8;
      bh[ni] = *reinterpret_cast<const s16x8*>(&bsh[lo]);
      bl[ni] = *reinterpret_cast<const s16x8*>(&bsl[lo]);
    }

    #pragma unroll
    for (int mi = 0; mi < 2; ++mi)
      #pragma unroll
      for (int ni = 0; ni < 8; ++ni) {
        acc[mi][ni] = __builtin_amdgcn_mfma_f32_16x16x32_bf16(ah[mi], bh[ni], acc[mi][ni], 0, 0, 0);
        acc[mi][ni] = __builtin_amdgcn_mfma_f32_16x16x32_bf16(ah[mi], bl[ni], acc[mi][ni], 0, 0, 0);
        acc[mi][ni] = __builtin_amdgcn_mfma_f32_16x16x32_bf16(al[mi], bh[ni], acc[mi][ni], 0, 0, 0);
      }
  }
  __syncthreads();   // all waves done reading B-LDS before xs is overwritten

  float bav[8], bmv[8];
  #pragma unroll
  for (int ni = 0; ni < 8; ++ni) {
    bav[ni] = ba[ni * 16 + l15];
    bmv[ni] = bmw[ni * 16 + l15];
  }

  #pragma unroll
  for (int mi = 0; mi < 2; ++mi) {
    #pragma unroll
    for (int r = 0; r < 4; ++r) {
      int lr = w * 32 + mi * 16 + lg * 4 + r;
      int grow = base + lr;
      if (grow >= n) continue;
      float msk = deg[grow] > 0 ? 1.0f : 0.0f;
      #pragma unroll
      for (int ni = 0; ni < 8; ++ni)
        xs[lr * 129 + ni * 16 + l15] =
            fmaxf(acc[mi][ni][r] + bav[ni] + msk * bmv[ni], 0.0f);
    }
  }
  __syncthreads();

  const int r = tid >> 1;
  const int half = tid & 1;
  const int grow = base + r;
  if (grow < n) {
    const float* wb = wl + half * 1280;
    float a[10] = {};
    for (int k = 0; k < 128; ++k) {
      float x = xs[r * 129 + k];
      #pragma unroll
      for (int j = 0; j < 10; ++j) a[j] = fmaf(x, wb[k * 10 + j], a[j]);
    }
    float* op = pt + (size_t)grow * 20 + half * 10;
    if (half) {
      #pragma unroll
      for (int j = 0; j < 10; ++j) op[j] = a[j] + bp[j];
    } else {
      #pragma unroll
      for (int j = 0; j < 10; ++j) op[j] = a[j];
    }
  }
}

// ---------------------------------------------------------------------------
// Edge predictor (bp pre-folded)
// ---------------------------------------------------------------------------
__global__ __launch_bounds__(256) void pred_edge_kernel(
    const float* __restrict__ pt, const int* __restrict__ src, const int* __restrict__ dst,
    float* __restrict__ out, int E)
{
  int idx = blockIdx.x * 256 + threadIdx.x;
  if (idx >= E * 5) return;
  int e = idx / 5;
  int jj = idx - e * 5;
  int s = src[e], d = dst[e];
  const float2* p2 = (const float2*)pt;
  float2 a = p2[(size_t)s * 10 + jj];
  float2 b = p2[(size_t)d * 10 + 5 + jj];
  ((float2*)out)[idx] = make_float2(a.x + b.x, a.y + b.y);
}

extern "C" void kernel_launch(void* const* d_in, const int* in_sizes, int n_in,
                              void* d_out, int out_size, void* d_ws, size_t ws_size,
                              hipStream_t stream) {
  const float* nfeats = (const float*)d_in[0];
  const float* efeats = (const float*)d_in[1];
  const int*   src    = (const int*)d_in[2];
  const int*   dst    = (const int*)d_in[3];
  const float* Wm1 = (const float*)d_in[4];
  const float* bm1 = (const float*)d_in[5];
  const float* Wa1 = (const float*)d_in[6];
  const float* ba1 = (const float*)d_in[7];
  const float* Wm2 = (const float*)d_in[8];
  const float* bm2 = (const float*)d_in[9];
  const float* Wa2 = (const float*)d_in[10];
  const float* ba2 = (const float*)d_in[11];
  const float* Wp  = (const float*)d_in[12];
  const float* bp  = (const float*)d_in[13];

  const int N = in_sizes[0] / 64;
  const int E = in_sizes[2];
  const int nblk = (N + 255) / 256;

  // ---- int region (R5..R12-proven layout) ----
  int* ip     = (int*)d_ws;
  int* deg_i  = ip;                                  // N
  int* rp     = ip + (size_t)N;                      // N+1 (padded to +4)
  int* scr    = ip + 2 * (size_t)N + 4 + E;          // 2N+512 CSR scratch
  int* excl   = scr;                                 // N
  int* cursor = scr + (size_t)N;                     // N
  int* bsum   = scr + 2 * (size_t)N;                 // 256

  // ---- plane region (R12-proven layout) ----
  size_t fbase = (4 * (size_t)N + 516 + (size_t)E + 3) & ~(size_t)3;
  float* fp   = (float*)d_ws;
  u16* mEh  = (u16*)(fp + fbase);                       // N*64 u16
  u16* mEl  = mEh + (size_t)N * 64;                     // N*64 u16
  float* pt = fp + fbase + (size_t)N * 64;              // N*20 f32 (overlays mH1 slot)
  u16* mH1h = (u16*)pt;                                 // N*64 u16
  u16* mH1l = mH1h + (size_t)N * 64;                    // N*64 u16
  u16* mH2h = (u16*)(fp + fbase + (size_t)N * 128);     // N*128 u16
  u16* mH2l = mH2h + (size_t)N * 128;                   // N*128 u16
  u16* h1h  = (u16*)(fp + fbase + (size_t)N * 384);     // N*128 u16
  u16* h1l  = h1h + (size_t)N * 128;                    // N*128 u16
  float* out = (float*)d_out;

  // es (int2), weights, nf planes appended after float slots
  int2*  es   = (int2*)(fp + fbase + (size_t)N * 512);
  float* wst  = fp + fbase + (size_t)N * 512 + 2 * (size_t)E;
  float* bmw1 = wst;                    // 128
  float* bmw2 = bmw1 + 128;             // 128
  u16* w1h = (u16*)(bmw2 + 128);        // [128][192]
  u16* w1l = w1h + 192 * 128;
  u16* w2h = w1l + 192 * 128;           // [128][320]
  u16* w2l = w2h + 320 * 128;
  u16* nfh = w2l + 320 * 128;           // N*64 u16
  u16* nfl = nfh + (size_t)N * 64;      // N*64 u16

  hipMemsetAsync(deg_i, 0, (size_t)N * sizeof(int), stream);

  int gridE  = (E + 255) / 256;
  int gridN  = (N + 127) / 128;          // 128-row GEMM blocks (R12-proven)
  int gridNW = ((N * 64) + 255) / 256;
  int npack  = (N * 64 + 255) / 256;

  // fused prep: weight prep + nfeats plane split + degree histogram
  prep_kernel<<<257 + npack + gridE, 256, 0, stream>>>(
      Wm1, Wa1, bm1, Wm2, Wa2, bm2, bmw1, bmw2, w1h, w1l, w2h, w2l,
      nfeats, nfh, nfl, N * 64, dst, deg_i, E, npack);

  // CSR build
  scan_blk_kernel<<<nblk, 256, 0, stream>>>(deg_i, excl, bsum, N);
  finalize2_kernel<<<(N + 256) / 256, 256, 0, stream>>>(excl, bsum, nblk, rp, cursor, N, E);
  scatter_kernel<<<gridE, 256, 0, stream>>>(dst, src, cursor, es, E);

  // layer 1
  csr_agg_l1_kernel<<<gridNW, 256, 0, stream>>>(
      efeats, nfh, es, rp, mEh, mEl, mH1h, mH1l, N);
  fgemm_kernel<64, 64, 64><<<gridN, 256, 0, stream>>>(
      nfh, nfl, mH1h, mH1l, mEh, mEl, w1h, w1l, ba1, bmw1, deg_i, h1h, h1l, N);

  // layer 2 (+ fused predictor projection; h2 never materialized)
  csr_agg128_kernel<<<gridNW, 256, 0, stream>>>(h1h, es, rp, mH2h, mH2l, N);
  fgemm2_pred_kernel<<<gridN, 256, 0, stream>>>(
      h1h, h1l, mH2h, mH2l, mEh, mEl, w2h, w2l, ba2, bmw2, deg_i, Wp, bp, pt, N);

  // edge scores
  pred_edge_kernel<<<(E * 5 + 255) / 256, 256, 0, stream>>>(pt, src, dst, out, E);
}